// Round 1
// baseline (77.560 us; speedup 1.0000x reference)
//
#include <hip/hip_runtime.h>
#include <math.h>

#define FF 512
#define SIGMAINV 7000.0f
#define EPSF 1e-10f
#define NW 8           // waves per block
#define FPW (FF / NW)  // faces per wave chunk = 64

// out layout: imrender [0,49152) ; improb [49152,65536) ; normal1 [65536,67072)
__global__ __launch_bounds__(512, 1) void vcrender_kernel(
    const float* __restrict__ points,   // 256*3
    const float* __restrict__ colors,   // 256*3
    const float* __restrict__ rot,      // 3*3
    const float* __restrict__ cpos,     // 3
    const float* __restrict__ proj,     // 3
    const int*   __restrict__ faces,    // 512*3
    float* __restrict__ out)
{
#pragma clang fp contract(off)
    // per-face record, stride 24:
    // 0..5: x0 y0 x1 y1 x2 y2 (screen)  6..8: z0 z1 z2 (cam)
    // 9: 1/denom  10: front&valid
    // 11..19: per-edge abx aby 1/(ab2+eps)
    // 20..23: bbox minx maxx miny maxy (inflated; empty if !fv)
    __shared__ float sface[FF * 24];
    __shared__ float redz[NW * 64];
    __shared__ int   redi[NW * 64];
    __shared__ float redp[NW * 64];

    const int tid = threadIdx.x;

    // ---------------- per-face setup: one face per thread ----------------
    {
        const int f = tid;  // 512 threads == 512 faces
        const int i0 = faces[f * 3 + 0];
        const int i1 = faces[f * 3 + 1];
        const int i2 = faces[f * 3 + 2];
        const float r00 = rot[0], r01 = rot[1], r02 = rot[2];
        const float r10 = rot[3], r11 = rot[4], r12 = rot[5];
        const float r20 = rot[6], r21 = rot[7], r22 = rot[8];
        const float cx = cpos[0], cy = cpos[1], cz = cpos[2];
        const float pjx = proj[0], pjy = proj[1], pjz = proj[2];

        float camx[3], camy[3], camz[3], sx[3], sy[3];
        const int vidx[3] = {i0, i1, i2};
        for (int k = 0; k < 3; ++k) {
            const int vi = vidx[k];
            const float ax = points[vi * 3 + 0] - cx;
            const float ay = points[vi * 3 + 1] - cy;
            const float az = points[vi * 3 + 2] - cz;
            const float X = r00 * ax + r01 * ay + r02 * az;
            const float Y = r10 * ax + r11 * ay + r12 * az;
            const float Z = r20 * ax + r21 * ay + r22 * az;
            camx[k] = X; camy[k] = Y; camz[k] = Z;
            const float zz = Z * pjz;
            sx[k] = (X * pjx) / zz;
            sy[k] = (Y * pjy) / zz;
        }
        // face normal in cam space
        const float e1x = camx[1] - camx[0], e1y = camy[1] - camy[0], e1z = camz[1] - camz[0];
        const float e2x = camx[2] - camx[0], e2y = camy[2] - camy[0], e2z = camz[2] - camz[0];
        const float nx = e1y * e2z - e1z * e2y;
        const float ny = e1z * e2x - e1x * e2z;
        const float nz = e1x * e2y - e1y * e2x;
        const float nlen = sqrtf(nx * nx + ny * ny + nz * nz + 1e-8f);
        const float ninv = 1.0f / (nlen + 1e-15f);
        if (blockIdx.x == 0) {
            out[65536 + f * 3 + 0] = nx * ninv;
            out[65536 + f * 3 + 1] = ny * ninv;
            out[65536 + f * 3 + 2] = nz * ninv;
        }
        const float x0 = sx[0], y0 = sy[0], x1 = sx[1], y1 = sy[1], x2 = sx[2], y2 = sy[2];
        const float area = (x1 - x0) * (y2 - y0) - (x2 - x0) * (y1 - y0);
        const bool valid = fabsf(area) > EPSF;
        const float denom = valid ? area : EPSF;
        const float invd = 1.0f / denom;
        const bool fv = (nz > 0.0f) && valid;

        float* r = &sface[f * 24];
        r[0] = x0; r[1] = y0; r[2] = x1; r[3] = y1; r[4] = x2; r[5] = y2;
        r[6] = camz[0]; r[7] = camz[1]; r[8] = camz[2];
        r[9] = invd; r[10] = fv ? 1.0f : 0.0f;
        const float ab0x = x1 - x0, ab0y = y1 - y0;
        const float ab1x = x2 - x1, ab1y = y2 - y1;
        const float ab2x = x0 - x2, ab2y = y0 - y2;
        r[11] = ab0x; r[12] = ab0y; r[13] = 1.0f / (ab0x * ab0x + ab0y * ab0y + EPSF);
        r[14] = ab1x; r[15] = ab1y; r[16] = 1.0f / (ab1x * ab1x + ab1y * ab1y + EPSF);
        r[17] = ab2x; r[18] = ab2y; r[19] = 1.0f / (ab2x * ab2x + ab2y * ab2y + EPSF);
        // inflated bbox: outside it, exp(-d2*SIGMAINV) < 6e-14 -> skip face
        const float RM = 0.0660f;  // > sqrt(30/7000)
        float bx0, bx1, by0, by1;
        if (fv) {
            bx0 = fminf(fminf(x0, x1), x2) - RM;
            bx1 = fmaxf(fmaxf(x0, x1), x2) + RM;
            by0 = fminf(fminf(y0, y1), y2) - RM;
            by1 = fmaxf(fmaxf(y0, y1), y2) + RM;
        } else {
            bx0 = 1e30f; bx1 = -1e30f; by0 = 1e30f; by1 = -1e30f;  // empty
        }
        r[20] = bx0; r[21] = bx1; r[22] = by0; r[23] = by1;
    }
    __syncthreads();

    // ---------------- pixel x face-chunk loop ----------------
    const int wv   = tid >> 6;        // 0..7 : face chunk
    const int lane = tid & 63;        // 0..63: pixel within block
    const int pix  = blockIdx.x * 64 + lane;   // 0..16383
    const float px = ((pix & 127) + 0.5f) * (2.0f / 128.0f) - 1.0f;
    const float py = 1.0f - ((pix >> 7) + 0.5f) * (2.0f / 128.0f);

    float zmin = INFINITY;
    int   fmin = 0;
    float prod = 1.0f;

    const int fbeg = wv * FPW;
    for (int f = fbeg; f < fbeg + FPW; ++f) {
        const float* r = &sface[f * 24];
        const float bx0 = r[20], bx1 = r[21], by0 = r[22], by1 = r[23];
        if (px >= bx0 && px <= bx1 && py >= by0 && py <= by1) {
            const float x0 = r[0], y0 = r[1], x1 = r[2], y1 = r[3], x2 = r[4], y2 = r[5];
            const float invd = r[9];
            const float w0 = ((x1 - px) * (y2 - py) - (x2 - px) * (y1 - py)) * invd;
            const float w1 = ((x2 - px) * (y0 - py) - (x0 - px) * (y2 - py)) * invd;
            const float w2 = 1.0f - w0 - w1;
            const bool inside = (w0 >= 0.0f) && (w1 >= 0.0f) && (w2 >= 0.0f);
            const float z = w0 * r[6] + w1 * r[7] + w2 * r[8];
            if (inside && z < zmin) { zmin = z; fmin = f; }
            // min squared distance to the 3 edges
            float apx, apy, t, dx, dy;
            apx = px - x0; apy = py - y0;
            t = fminf(fmaxf((apx * r[11] + apy * r[12]) * r[13], 0.0f), 1.0f);
            dx = apx - t * r[11]; dy = apy - t * r[12];
            float d2 = dx * dx + dy * dy;
            apx = px - x1; apy = py - y1;
            t = fminf(fmaxf((apx * r[14] + apy * r[15]) * r[16], 0.0f), 1.0f);
            dx = apx - t * r[14]; dy = apy - t * r[15];
            d2 = fminf(d2, dx * dx + dy * dy);
            apx = px - x2; apy = py - y2;
            t = fminf(fmaxf((apx * r[17] + apy * r[18]) * r[19], 0.0f), 1.0f);
            dx = apx - t * r[17]; dy = apy - t * r[18];
            d2 = fminf(d2, dx * dx + dy * dy);
            d2 = inside ? 0.0f : d2;
            prod *= (1.0f - __expf(-d2 * SIGMAINV));
        }
    }

    redz[wv * 64 + lane] = zmin;
    redi[wv * 64 + lane] = fmin;
    redp[wv * 64 + lane] = prod;
    __syncthreads();

    // ---------------- combine chunks + epilogue (wave 0) ----------------
    if (wv == 0) {
        float z = zmin; int fi = fmin; float pr = prod;
        for (int c = 1; c < NW; ++c) {
            const float zc = redz[c * 64 + lane];
            const float pc = redp[c * 64 + lane];
            const int   ic = redi[c * 64 + lane];
            if (zc < z) { z = zc; fi = ic; }   // ascending chunk: first-min tiebreak
            pr *= pc;
        }
        float fr = 0.0f, fg = 0.0f, fb = 0.0f;
        if (z < INFINITY) {  // hit
            const float* r = &sface[fi * 24];
            const float x0 = r[0], y0 = r[1], x1 = r[2], y1 = r[3], x2 = r[4], y2 = r[5];
            const float invd = r[9];
            const float w0 = ((x1 - px) * (y2 - py) - (x2 - px) * (y1 - py)) * invd;
            const float w1 = ((x2 - px) * (y0 - py) - (x0 - px) * (y2 - py)) * invd;
            const float w2 = 1.0f - w0 - w1;
            const int i0 = faces[fi * 3 + 0], i1 = faces[fi * 3 + 1], i2 = faces[fi * 3 + 2];
            fr = w0 * colors[i0 * 3 + 0] + w1 * colors[i1 * 3 + 0] + w2 * colors[i2 * 3 + 0];
            fg = w0 * colors[i0 * 3 + 1] + w1 * colors[i1 * 3 + 1] + w2 * colors[i2 * 3 + 1];
            fb = w0 * colors[i0 * 3 + 2] + w1 * colors[i1 * 3 + 2] + w2 * colors[i2 * 3 + 2];
        }
        out[pix * 3 + 0] = fr;
        out[pix * 3 + 1] = fg;
        out[pix * 3 + 2] = fb;
        out[3 * 16384 + pix] = 1.0f - pr;
    }
}

extern "C" void kernel_launch(void* const* d_in, const int* in_sizes, int n_in,
                              void* d_out, int out_size, void* d_ws, size_t ws_size,
                              hipStream_t stream) {
    const float* points = (const float*)d_in[0];
    const float* colors = (const float*)d_in[1];
    const float* rot    = (const float*)d_in[2];
    const float* cpos   = (const float*)d_in[3];
    const float* proj   = (const float*)d_in[4];
    const int*   faces  = (const int*)d_in[5];
    float* out = (float*)d_out;
    vcrender_kernel<<<256, 512, 0, stream>>>(points, colors, rot, cpos, proj, faces, out);
}